// Round 2
// baseline (405.178 us; speedup 1.0000x reference)
//
#include <hip/hip_runtime.h>

// Problem constants (match reference)
#define BATCH   64
#define GH      52
#define GWID    52
#define HW      2704          // GH*GW
#define NA      5
#define NC      80
#define MAXB    30
#define CH_STRIDE HW          // channel stride in reshaped net_out
#define A_STRIDE  (85*HW)     // 229840
#define B_STRIDE  (NA*85*HW)  // 1149200

// grid: (11, 320), block 256.  blockIdx.y = b*NA + a
__global__ __launch_bounds__(256) void yolo_main(
    const float* __restrict__ net_out,   // (B, A, 85, HW) view
    const float* __restrict__ targets,   // (B, A, 6, HW)
    const float* __restrict__ amask,     // (B, A, HW)
    const float* __restrict__ tboxes,    // (B, MAXB, 4)
    const float* __restrict__ anchors,   // (A, 2)
    float* __restrict__ partial)         // (gridDim.y * gridDim.x)
{
    __shared__ float tb[MAXB * 4];
    __shared__ float wred[4];

    const int ba  = blockIdx.y;
    const int b   = ba / NA;
    const int a   = ba - b * NA;
    const int tid = threadIdx.x;

    if (tid < MAXB * 4) tb[tid] = tboxes[(size_t)b * (MAXB * 4) + tid];
    __syncthreads();

    const int p = blockIdx.x * 256 + tid;
    float local = 0.f;

    if (p < HW) {
        const size_t nb    = (size_t)b * B_STRIDE + (size_t)a * A_STRIDE + p;
        const size_t tbase = ((size_t)(b * NA + a) * 6) * HW + p;

        const float t_x   = targets[tbase];
        const float t_y   = targets[tbase + 1 * HW];
        const float t_w   = targets[tbase + 2 * HW];
        const float t_h   = targets[tbase + 3 * HW];
        const float t_c   = targets[tbase + 4 * HW];
        const int   t_cls = (int)targets[tbase + 5 * HW];

        const float am = amask[(size_t)(b * NA + a) * HW + p];

        const float zx = net_out[nb];
        const float zy = net_out[nb + 1 * CH_STRIDE];
        const float tw = net_out[nb + 2 * CH_STRIDE];
        const float th = net_out[nb + 3 * CH_STRIDE];
        const float zc = net_out[nb + 4 * CH_STRIDE];

        const float sx = 1.f / (1.f + __builtin_expf(-zx));
        const float sy = 1.f / (1.f + __builtin_expf(-zy));
        const float pc = 1.f / (1.f + __builtin_expf(-zc));

        // ---- coords loss (scale 5) ----
        const float ws = 2.f - t_w * t_h * (1.f / (416.f * 416.f));
        const float dx = sx - t_x, dy = sy - t_y, dw = tw - t_w, dh = th - t_h;
        const float coords = (dx * dx + dy * dy + dw * dw + dh * dh) * ws * am;

        // ---- focal conf loss ----
        // log(pc) = -log(1+e^{-zc}); log(1-pc) = -log(1+e^{zc})  (no log1pf on device)
        const float log_pc   = -__builtin_logf(1.f + __builtin_expf(-zc));
        const float log_1mpc = -__builtin_logf(1.f + __builtin_expf(zc));
        const float bce = -(t_c * log_pc + (1.f - t_c) * log_1mpc);
        const float pt  = __builtin_expf(-bce);
        const float omp = 1.f - pt;
        const float fl  = omp * omp * bce;

        // ---- pred box + IoU max over true boxes ----
        const float aw = anchors[a * 2 + 0];
        const float ah = anchors[a * 2 + 1];
        const float px = (sx + (float)(p % GWID)) * (416.f / (float)GWID);
        const float py = (sy + (float)(p / GWID)) * (416.f / (float)GH);
        const float pw = __builtin_expf(tw) * aw;
        const float ph = __builtin_expf(th) * ah;
        const float x1 = px - pw * 0.5f;
        const float y1 = py - ph * 0.5f;
        const float x2 = x1 + pw;
        const float y2 = y1 + ph;
        const float a1 = (x2 - x1) * (y2 - y1);

        float ioumax = 0.f;
        #pragma unroll
        for (int k = 0; k < MAXB; ++k) {
            const float bx1 = tb[k * 4 + 0];
            const float by1 = tb[k * 4 + 1];
            const float bx2 = tb[k * 4 + 2];
            const float by2 = tb[k * 4 + 3];
            const float tlx = fmaxf(x1, bx1);
            const float tly = fmaxf(y1, by1);
            const float brx = fminf(x2, bx2);
            const float bry = fminf(y2, by2);
            const float wi  = fmaxf(brx - tlx, 0.f);
            const float hi  = fmaxf(bry - tly, 0.f);
            const float inter = wi * hi;
            const float a2  = (bx2 - bx1) * (by2 - by1);
            const float iou = inter / (a1 + a2 - inter + 1e-5f);
            ioumax = fmaxf(ioumax, iou);
        }

        const float noobj = (ioumax < 0.5f) ? (1.f - am) : 0.f;

        local = 5.0f * coords + 5.0f * am * fl + noobj * fl;

        // ---- class loss: only where mask is set (~2% of lanes) ----
        if (am > 0.f) {
            float lg[NC];
            #pragma unroll
            for (int c = 0; c < NC; ++c)
                lg[c] = net_out[nb + (size_t)(5 + c) * CH_STRIDE];
            float m = lg[0];
            #pragma unroll
            for (int c = 1; c < NC; ++c) m = fmaxf(m, lg[c]);
            float s = 0.f;
            #pragma unroll
            for (int c = 0; c < NC; ++c) s += __builtin_expf(lg[c] - m);
            float vt = 0.f;
            #pragma unroll
            for (int c = 0; c < NC; ++c) vt = (c == t_cls) ? lg[c] : vt;
            local += -(vt - m - __builtin_logf(s)) * am;   // CLASS_SCALE = 1
        }
    }

    // ---- block reduction ----
    #pragma unroll
    for (int off = 32; off > 0; off >>= 1)
        local += __shfl_down(local, off, 64);
    const int wid  = tid >> 6;
    const int lane = tid & 63;
    if (lane == 0) wred[wid] = local;
    __syncthreads();
    if (tid == 0) {
        partial[(size_t)blockIdx.y * gridDim.x + blockIdx.x] =
            wred[0] + wred[1] + wred[2] + wred[3];
    }
}

__global__ __launch_bounds__(256) void yolo_reduce(
    const float* __restrict__ partial, int n, float* __restrict__ out)
{
    __shared__ double sred[4];
    const int tid = threadIdx.x;
    double s = 0.0;
    for (int i = tid; i < n; i += 256) s += (double)partial[i];
    #pragma unroll
    for (int off = 32; off > 0; off >>= 1)
        s += __shfl_down(s, off, 64);
    const int wid  = tid >> 6;
    const int lane = tid & 63;
    if (lane == 0) sred[wid] = s;
    __syncthreads();
    if (tid == 0) {
        const double tot = sred[0] + sred[1] + sred[2] + sred[3];
        out[0] = (float)(tot / (double)BATCH);
    }
}

extern "C" void kernel_launch(void* const* d_in, const int* in_sizes, int n_in,
                              void* d_out, int out_size, void* d_ws, size_t ws_size,
                              hipStream_t stream) {
    const float* net_out = (const float*)d_in[0];
    const float* targets = (const float*)d_in[1];
    const float* amask   = (const float*)d_in[2];
    const float* tboxes  = (const float*)d_in[3];
    const float* anchors = (const float*)d_in[4];
    float* partial = (float*)d_ws;
    float* out = (float*)d_out;

    const int gx = (HW + 255) / 256;          // 11
    dim3 grid(gx, BATCH * NA);                // (11, 320) = 3520 blocks
    yolo_main<<<grid, 256, 0, stream>>>(net_out, targets, amask, tboxes, anchors, partial);
    yolo_reduce<<<1, 256, 0, stream>>>(partial, gx * BATCH * NA, out);
}

// Round 3
// 385.044 us; speedup vs baseline: 1.0523x; 1.0523x over previous
//
#include <hip/hip_runtime.h>

// Problem constants (match reference)
#define BATCH   64
#define GH      52
#define GWID    52
#define HW      2704          // GH*GW
#define NA      5
#define NC      80
#define MAXB    30
#define CH_STRIDE HW          // channel stride in reshaped net_out
#define A_STRIDE  (85*HW)     // 229840
#define B_STRIDE  (NA*85*HW)  // 1149200

// grid: (11, 320), block 256.  blockIdx.y = b*NA + a
// Class loss is wave-cooperative: no per-lane lg[80] array (keeps VGPRs low
// so occupancy hides the scattered class-channel load latency).
__global__ __launch_bounds__(256) void yolo_main(
    const float* __restrict__ net_out,   // (B, A, 85, HW) view
    const float* __restrict__ targets,   // (B, A, 6, HW)
    const float* __restrict__ amask,     // (B, A, HW)
    const float* __restrict__ tboxes,    // (B, MAXB, 4)
    const float* __restrict__ anchors,   // (A, 2)
    float* __restrict__ partial)         // (gridDim.y * gridDim.x)
{
    __shared__ float tb[MAXB * 4];
    __shared__ float wred[4];

    const int ba  = blockIdx.y;
    const int b   = ba / NA;
    const int a   = ba - b * NA;
    const int tid = threadIdx.x;
    const int lane = tid & 63;

    if (tid < MAXB * 4) tb[tid] = tboxes[(size_t)b * (MAXB * 4) + tid];
    __syncthreads();

    // Clamp tail so ALL 64 lanes stay active (wave-collective ops below).
    const int  p_raw = blockIdx.x * 256 + tid;
    const bool valid = (p_raw < HW);
    const int  p     = valid ? p_raw : (HW - 1);

    const size_t nbase = (size_t)b * B_STRIDE + (size_t)a * A_STRIDE;
    const size_t nb    = nbase + p;
    const size_t tbase = ((size_t)ba * 6) * HW + p;

    const float t_x   = targets[tbase];
    const float t_y   = targets[tbase + 1 * HW];
    const float t_w   = targets[tbase + 2 * HW];
    const float t_h   = targets[tbase + 3 * HW];
    const float t_c   = targets[tbase + 4 * HW];
    const int   t_cls = (int)targets[tbase + 5 * HW];

    float am = amask[(size_t)ba * HW + p];
    if (!valid) am = 0.f;

    const float zx = net_out[nb];
    const float zy = net_out[nb + 1 * CH_STRIDE];
    const float tw = net_out[nb + 2 * CH_STRIDE];
    const float th = net_out[nb + 3 * CH_STRIDE];
    const float zc = net_out[nb + 4 * CH_STRIDE];

    const float sx = 1.f / (1.f + __builtin_expf(-zx));
    const float sy = 1.f / (1.f + __builtin_expf(-zy));

    // ---- coords loss (scale 5) ----
    const float ws = 2.f - t_w * t_h * (1.f / (416.f * 416.f));
    const float dx = sx - t_x, dy = sy - t_y, dw = tw - t_w, dh = th - t_h;
    const float coords = (dx * dx + dy * dy + dw * dw + dh * dh) * ws * am;

    // ---- focal conf loss ----
    // log(pc) = -log(1+e^{-zc}); log(1-pc) = -log(1+e^{zc})  (no log1pf on device)
    const float log_pc   = -__builtin_logf(1.f + __builtin_expf(-zc));
    const float log_1mpc = -__builtin_logf(1.f + __builtin_expf(zc));
    const float bce = -(t_c * log_pc + (1.f - t_c) * log_1mpc);
    const float pt  = __builtin_expf(-bce);
    const float omp = 1.f - pt;
    const float fl  = omp * omp * bce;

    // ---- pred box + IoU max over true boxes ----
    const float aw = anchors[a * 2 + 0];
    const float ah = anchors[a * 2 + 1];
    const float px = (sx + (float)(p % GWID)) * (416.f / (float)GWID);
    const float py = (sy + (float)(p / GWID)) * (416.f / (float)GH);
    const float pw = __builtin_expf(tw) * aw;
    const float ph = __builtin_expf(th) * ah;
    const float x1 = px - pw * 0.5f;
    const float y1 = py - ph * 0.5f;
    const float x2 = x1 + pw;
    const float y2 = y1 + ph;
    const float a1 = (x2 - x1) * (y2 - y1);

    float ioumax = 0.f;
    #pragma unroll
    for (int k = 0; k < MAXB; ++k) {
        const float bx1 = tb[k * 4 + 0];
        const float by1 = tb[k * 4 + 1];
        const float bx2 = tb[k * 4 + 2];
        const float by2 = tb[k * 4 + 3];
        const float tlx = fmaxf(x1, bx1);
        const float tly = fmaxf(y1, by1);
        const float brx = fminf(x2, bx2);
        const float bry = fminf(y2, by2);
        const float wi  = fmaxf(brx - tlx, 0.f);
        const float hi  = fmaxf(bry - tly, 0.f);
        const float inter = wi * hi;
        const float a2  = (bx2 - bx1) * (by2 - by1);
        const float iou = inter / (a1 + a2 - inter + 1e-5f);
        ioumax = fmaxf(ioumax, iou);
    }

    const float noobj = (ioumax < 0.5f) ? (1.f - am) : 0.f;

    float local = valid ? (5.0f * coords + 5.0f * am * fl + noobj * fl) : 0.f;

    // ---- class loss: wave-cooperative over masked cells (~2% density) ----
    unsigned long long mb = __ballot(am > 0.f);
    while (mb) {
        const int src = __ffsll((long long)mb) - 1;
        mb &= mb - 1;
        const int   p_s  = __shfl(p, src, 64);
        const float am_s = __shfl(am, src, 64);
        const int   tc_s = __shfl(t_cls, src, 64);

        const size_t cb = nbase + (size_t)5 * CH_STRIDE + p_s;
        const float v0 = net_out[cb + (size_t)lane * CH_STRIDE];
        const float v1 = (lane < NC - 64)
                       ? net_out[cb + (size_t)(64 + lane) * CH_STRIDE]
                       : -1e30f;

        float mx = fmaxf(v0, v1);
        #pragma unroll
        for (int off = 32; off > 0; off >>= 1)
            mx = fmaxf(mx, __shfl_xor(mx, off, 64));

        float e = __builtin_expf(v0 - mx)
                + ((lane < NC - 64) ? __builtin_expf(v1 - mx) : 0.f);
        #pragma unroll
        for (int off = 32; off > 0; off >>= 1)
            e += __shfl_xor(e, off, 64);

        const float vt = (tc_s < 64) ? __shfl(v0, tc_s, 64)
                                     : __shfl(v1, tc_s - 64, 64);

        if ((int)lane == src)
            local += -(vt - mx - __builtin_logf(e)) * am_s;  // CLASS_SCALE = 1
    }

    // ---- block reduction ----
    #pragma unroll
    for (int off = 32; off > 0; off >>= 1)
        local += __shfl_down(local, off, 64);
    const int wid = tid >> 6;
    if (lane == 0) wred[wid] = local;
    __syncthreads();
    if (tid == 0) {
        partial[(size_t)blockIdx.y * gridDim.x + blockIdx.x] =
            wred[0] + wred[1] + wred[2] + wred[3];
    }
}

__global__ __launch_bounds__(256) void yolo_reduce(
    const float* __restrict__ partial, int n, float* __restrict__ out)
{
    __shared__ double sred[4];
    const int tid = threadIdx.x;
    double s = 0.0;
    for (int i = tid; i < n; i += 256) s += (double)partial[i];
    #pragma unroll
    for (int off = 32; off > 0; off >>= 1)
        s += __shfl_down(s, off, 64);
    const int wid  = tid >> 6;
    const int lane = tid & 63;
    if (lane == 0) sred[wid] = s;
    __syncthreads();
    if (tid == 0) {
        const double tot = sred[0] + sred[1] + sred[2] + sred[3];
        out[0] = (float)(tot / (double)BATCH);
    }
}

extern "C" void kernel_launch(void* const* d_in, const int* in_sizes, int n_in,
                              void* d_out, int out_size, void* d_ws, size_t ws_size,
                              hipStream_t stream) {
    const float* net_out = (const float*)d_in[0];
    const float* targets = (const float*)d_in[1];
    const float* amask   = (const float*)d_in[2];
    const float* tboxes  = (const float*)d_in[3];
    const float* anchors = (const float*)d_in[4];
    float* partial = (float*)d_ws;
    float* out = (float*)d_out;

    const int gx = (HW + 255) / 256;          // 11
    dim3 grid(gx, BATCH * NA);                // (11, 320) = 3520 blocks
    yolo_main<<<grid, 256, 0, stream>>>(net_out, targets, amask, tboxes, anchors, partial);
    yolo_reduce<<<1, 256, 0, stream>>>(partial, gx * BATCH * NA, out);
}